// Round 6
// baseline (323.117 us; speedup 1.0000x reference)
//
#include <hip/hip_runtime.h>

// CRITICAL: bit-exact replication of the numpy fp32 oracle requires NO FMA
// contraction (hipcc default -ffp-contract=fast-honor-pragmas would fuse).
#pragma clang fp contract(off)

#define D4    83521      // 17^4 entries per LUT (per channel)
#define HW    262144     // 512*512
#define NPIX  2097152    // 8*512*512
#define QREC  73984      // 17*17*16*16 quad records per LUT (64 B each)
#define RECN  69632      // 17*16*16*16 oct records per LUT (128 B each)
#define CBLK  64         // cooperative kernel: single-wave blocks

struct SrcPtrs { const float* p[6]; };

// ---------- oct packing, ALL 6 LUTS IN ONE LAUNCH ---------------------------
// Record e = ((i0*16 + i1)*16 + i2)*16 + i3 (i1,i2,i3 in [0,16), i0 in [0,17));
// slot g (float4) holds channels of corner (i1+((g>>2)&1), i2+((g>>1)&1),
// i3+(g&1)). A pixel's 16 corners = records R(i0) and R(i0)+4096 (i0+1),
// each ONE aligned 128 B line. One float4 slot per thread -> coalesced writes.
// r19: s derived from blockIdx (2176 blocks per LUT, grid exact) -> uniform
// scalar pointer select instead of per-thread division.
__global__ __launch_bounds__(256) void pack_oct_all(SrcPtrs sp,
                                                    float4* __restrict__ dst) {
    const int PER = RECN * 8;                 // 557056 slots per LUT
    int blk = blockIdx.x;
    int s = blk / 2176;                       // LUT index 0..5 (uniform/scalar)
    int j = blk * 256 + threadIdx.x;          // [0, 6*PER), grid exact
    int r = j - s * PER;
    int g = r & 7;                            // slot = b1*4 + b2*2 + b3
    int e = r >> 3;                           // record index
    int i3 = e & 15;
    int i2 = (e >> 4) & 15;
    int i1 = (e >> 8) & 15;
    int i0 = e >> 12;                         // [0,17)
    int o = i0 * 4913 + i1 * 289 + i2 * 17 + i3
          + ((g >> 2) & 1) * 289 + ((g >> 1) & 1) * 17 + (g & 1);
    const float* __restrict__ src = sp.p[s];
    float4 v;
    v.x = src[o];
    v.y = src[D4 + o];
    v.z = src[2 * D4 + o];
    v.w = (s != 5) ? src[3 * D4 + o] : 0.f;
    dst[j] = v;                               // fully coalesced 16 B/lane
}

// Cooperative fused 6-stage chain — BARRIER-FREE, OCT layout, HALF-LDS (r19).
// r17/r18 evidence: gather at the 2-lines/pixel/stage floor, but only 50% of
// the 34.5 TB/s L2 ceiling used (25.2M lines * 128 B / 187 us = 17.2 TB/s),
// VALUBusy 37%, occupancy 24% (LDS 17408 B -> 9 blocks/CU). Latency-hiding
// limited -> double residency by halving LDS WITHOUT touching the 16-deep
// load batch (r14's fatal mistake was splitting the loads; the batch below
// is byte-identical to r17). The exchange/accumulate splits by PIXEL halves:
// write v[0..7] (pixels 0..31) into a 32-row buffer, lanes 0..31 accumulate
// their full 16-corner sum (rows complete: all 64 lanes wrote their kidx);
// then write v[8..15] (pixels 32..63) into the SAME rows, lanes 32..63
// accumulate. All in-wave (DS ops program-ordered per wave, sched_barrier(0)
// pins compiler motion), no __syncthreads. Per-lane row content and the
// sequential accumulation are bit-identical to r17 (absmax 0.0).
// LDS 8704 B -> 18 blocks/CU; __launch_bounds__(64,4) raises the VGPR cap
// to 128 so v[8..15] staying live through phase A cannot re-split the batch.
__global__ __launch_bounds__(CBLK, 4) void fused_coop(const float* __restrict__ vi,
                                                      const float* __restrict__ ir,
                                                      const float4* __restrict__ luts,
                                                      float* __restrict__ out) {
#pragma clang fp contract(off)
    __shared__ float4 exch[32 * 17];    // 8704 B: 32 pixel-rows, stride 17

    int tid = threadIdx.x;              // == lane (single-wave block)
    int p = blockIdx.x * CBLK + tid;
    int b  = p >> 18;                   // HW = 2^18
    int hw = p & (HW - 1);
    int vbase = (b * 3) << 18;

    float x0 = vi[vbase + hw];
    float x1 = vi[vbase + HW + hw];
    float x2 = vi[vbase + 2 * HW + hw];
    float x3 = ir[p];

    int sub  = tid >> 4;                // which pixel of each 4-px group
    int kidx = tid & 15;                // corner code: b0=(k>>2)&1, b1=(k>>3)&1,
                                        //              b2=k&1,      b3=(k>>1)&1
    int b0   = (kidx >> 2) & 1;
    int slot = ((kidx >> 3) & 1) * 4 + (kidx & 1) * 2 + ((kidx >> 1) & 1);

    for (int s = 0; s < 6; ++s) {
        // per-lane LUT base folds in i0-record select + slot (addr calc once)
        const float4* __restrict__ lutS =
            luts + (size_t)s * (RECN * 8) + b0 * (4096 * 8) + slot;

        // ---- owner: indices + weights (exact round-6 arithmetic) ----
        x0 = fminf(fmaxf(x0, 0.f), 1.f);
        x1 = fminf(fmaxf(x1, 0.f), 1.f);
        x2 = fminf(fmaxf(x2, 0.f), 1.f);
        x3 = fminf(fmaxf(x3, 0.f), 1.f);
        float xs0 = x0 * 16.f;
        float xs1 = x1 * 16.f;
        float xs2 = x2 * 16.f;
        float xs3 = x3 * 16.f;
        int i0 = (int)xs0; i0 = i0 > 15 ? 15 : i0;
        int i1 = (int)xs1; i1 = i1 > 15 ? 15 : i1;
        int i2 = (int)xs2; i2 = i2 > 15 ? 15 : i2;
        int i3 = (int)xs3; i3 = i3 > 15 ? 15 : i3;
        float f0 = xs0 - (float)i0;     // mul-then-sub, contraction OFF
        float f1 = xs1 - (float)i1;
        float f2 = xs2 - (float)i2;
        float f3 = xs3 - (float)i3;
        float g0 = 1.f - f0;
        float g1 = 1.f - f1;
        float g2 = 1.f - f2;
        float g3 = 1.f - f3;
        float w01[4] = { g0 * g1, f0 * g1, g0 * f1, f0 * f1 };

        int r00 = ((i0 * 16 + i1) * 16 + i2) * 16 + i3;   // oct record index

        // ---- r00 exchange: pure in-wave shuffle, no LDS / no barrier ----
        int r0s[16];
#pragma unroll
        for (int t = 0; t < 16; ++t)
            r0s[t] = __shfl(r00, 4 * t + sub, 64);

        // ---- cooperative gather: 16 loads/lane, 8 x 128 B lines/instr ----
        // (byte-identical to r17 — the batch must stay intact)
        float4 v[16];
#pragma unroll
        for (int t = 0; t < 16; ++t)
            v[t] = lutS[(size_t)r0s[t] * 8];
        __builtin_amdgcn_sched_barrier(0);   // keep the 16-deep load batch intact

        float a0 = 0.f, a1 = 0.f, a2 = 0.f, a3 = 0.f;

        // ---- phase A: pixels 0..31 (rows 4t+sub, t=0..7) ----
#pragma unroll
        for (int t = 0; t < 8; ++t)
            exch[(4 * t + sub) * 17 + kidx] = v[t];
        __builtin_amdgcn_sched_barrier(0);   // pin write->read program order

        if (tid < 32) {
            const float4* myb = &exch[tid * 17];
#pragma unroll
            for (int hi = 0; hi < 2; ++hi) {     // b3
                float w3 = hi ? f3 : g3;
#pragma unroll
                for (int c = 0; c < 8; ++c) {    // b0=c&1, b1=(c>>1)&1, b2=c>>2
                    int k = ((c & 3) << 2) + ((c >> 2) + 2 * hi);
                    float4 vv = myb[k];
                    float w012 = w01[c & 3] * ((c >> 2) ? f2 : g2);
                    float w    = w012 * w3;
                    if (hi == 0 && c == 0) {
                        a0 = vv.x * w; a1 = vv.y * w; a2 = vv.z * w; a3 = vv.w * w;
                    } else {
                        a0 = a0 + vv.x * w; a1 = a1 + vv.y * w;
                        a2 = a2 + vv.z * w; a3 = a3 + vv.w * w;
                    }
                }
            }
        }
        __builtin_amdgcn_sched_barrier(0);   // phase-A reads before phase-B writes

        // ---- phase B: pixels 32..63 into the SAME 32 rows ----
#pragma unroll
        for (int t = 8; t < 16; ++t)
            exch[(4 * (t - 8) + sub) * 17 + kidx] = v[t];
        __builtin_amdgcn_sched_barrier(0);   // pin write->read program order

        if (tid >= 32) {
            const float4* myb = &exch[(tid - 32) * 17];
#pragma unroll
            for (int hi = 0; hi < 2; ++hi) {
                float w3 = hi ? f3 : g3;
#pragma unroll
                for (int c = 0; c < 8; ++c) {
                    int k = ((c & 3) << 2) + ((c >> 2) + 2 * hi);
                    float4 vv = myb[k];
                    float w012 = w01[c & 3] * ((c >> 2) ? f2 : g2);
                    float w    = w012 * w3;
                    if (hi == 0 && c == 0) {
                        a0 = vv.x * w; a1 = vv.y * w; a2 = vv.z * w; a3 = vv.w * w;
                    } else {
                        a0 = a0 + vv.x * w; a1 = a1 + vv.y * w;
                        a2 = a2 + vv.z * w; a3 = a3 + vv.w * w;
                    }
                }
            }
        }
        __builtin_amdgcn_sched_barrier(0);   // reads done before next stage's writes

        x0 = a0; x1 = a1; x2 = a2; x3 = a3;
    }

    out[vbase + hw]          = x0;
    out[vbase + HW + hw]     = x1;
    out[vbase + 2 * HW + hw] = x2;
}

// ---------- quad tier (proven r13, 285 us coop): fallback if ws < 53.5 MB ---
__global__ __launch_bounds__(256) void pack_quad(const float* __restrict__ src,
                                                 int n_ch,
                                                 float4* __restrict__ dst) {
    int e = blockIdx.x * 256 + threadIdx.x;
    if (e >= QREC) return;
    int i3 = e & 15;
    int i2 = (e >> 4) & 15;
    int t  = e >> 8;              // i0*17 + i1
    int i0 = t / 17;
    int i1 = t - i0 * 17;
    int base = i0 * 4913 + i1 * 289 + i2 * 17 + i3;
    float4* rec = dst + (size_t)e * 4;
#pragma unroll
    for (int g = 0; g < 4; ++g) {
        int o = base + (g & 1) * 17 + (g >> 1);
        float4 v;
        v.x = src[o];
        v.y = src[D4 + o];
        v.z = src[2 * D4 + o];
        v.w = (n_ch == 4) ? src[3 * D4 + o] : 0.f;
        rec[g] = v;
    }
}

__global__ __launch_bounds__(CBLK) void fused_coop_q(const float* __restrict__ vi,
                                                     const float* __restrict__ ir,
                                                     const float4* __restrict__ luts,
                                                     float* __restrict__ out) {
#pragma clang fp contract(off)
    __shared__ float4 exch[CBLK * 17];

    int tid = threadIdx.x;
    int p = blockIdx.x * CBLK + tid;
    int b  = p >> 18;
    int hw = p & (HW - 1);
    int vbase = (b * 3) << 18;

    float x0 = vi[vbase + hw];
    float x1 = vi[vbase + HW + hw];
    float x2 = vi[vbase + 2 * HW + hw];
    float x3 = ir[p];

    int rec     = (tid >> 2) & 3;
    int slot    = tid & 3;
    int rec_off = ((rec & 1) ? 4352 : 0) + ((rec & 2) ? 256 : 0);
    int sub     = tid >> 4;
    int kidx    = tid & 15;

    for (int s = 0; s < 6; ++s) {
        const float4* __restrict__ lutS =
            luts + (size_t)s * QREC * 4 + (size_t)rec_off * 4 + slot;

        x0 = fminf(fmaxf(x0, 0.f), 1.f);
        x1 = fminf(fmaxf(x1, 0.f), 1.f);
        x2 = fminf(fmaxf(x2, 0.f), 1.f);
        x3 = fminf(fmaxf(x3, 0.f), 1.f);
        float xs0 = x0 * 16.f;
        float xs1 = x1 * 16.f;
        float xs2 = x2 * 16.f;
        float xs3 = x3 * 16.f;
        int i0 = (int)xs0; i0 = i0 > 15 ? 15 : i0;
        int i1 = (int)xs1; i1 = i1 > 15 ? 15 : i1;
        int i2 = (int)xs2; i2 = i2 > 15 ? 15 : i2;
        int i3 = (int)xs3; i3 = i3 > 15 ? 15 : i3;
        float f0 = xs0 - (float)i0;
        float f1 = xs1 - (float)i1;
        float f2 = xs2 - (float)i2;
        float f3 = xs3 - (float)i3;
        float g0 = 1.f - f0;
        float g1 = 1.f - f1;
        float g2 = 1.f - f2;
        float g3 = 1.f - f3;
        float w01[4] = { g0 * g1, f0 * g1, g0 * f1, f0 * f1 };

        int r00 = ((i0 * 17 + i1) * 16 + i2) * 16 + i3;

        int r0s[16];
#pragma unroll
        for (int t = 0; t < 16; ++t)
            r0s[t] = __shfl(r00, 4 * t + sub, 64);

        float4 v[16];
#pragma unroll
        for (int t = 0; t < 16; ++t)
            v[t] = lutS[(size_t)r0s[t] * 4];
        __builtin_amdgcn_sched_barrier(0);

#pragma unroll
        for (int t = 0; t < 16; ++t)
            exch[(4 * t + sub) * 17 + kidx] = v[t];
        __builtin_amdgcn_sched_barrier(0);

        const float4* myb = &exch[tid * 17];
        float a0 = 0.f, a1 = 0.f, a2 = 0.f, a3 = 0.f;
#pragma unroll
        for (int hi = 0; hi < 2; ++hi) {
            float w3 = hi ? f3 : g3;
#pragma unroll
            for (int c = 0; c < 8; ++c) {
                int k = ((c & 3) << 2) + ((c >> 2) + 2 * hi);
                float4 vv = myb[k];
                float w012 = w01[c & 3] * ((c >> 2) ? f2 : g2);
                float w    = w012 * w3;
                if (hi == 0 && c == 0) {
                    a0 = vv.x * w; a1 = vv.y * w; a2 = vv.z * w; a3 = vv.w * w;
                } else {
                    a0 = a0 + vv.x * w; a1 = a1 + vv.y * w;
                    a2 = a2 + vv.z * w; a3 = a3 + vv.w * w;
                }
            }
        }
        __builtin_amdgcn_sched_barrier(0);
        x0 = a0; x1 = a1; x2 = a2; x3 = a3;
    }

    out[vbase + hw]          = x0;
    out[vbase + HW + hw]     = x1;
    out[vbase + 2 * HW + hw] = x2;
}

// ---------- raw fallback (no workspace) -------------------------------------
__global__ __launch_bounds__(256) void fused_fallback(const float* __restrict__ vi,
                                                      const float* __restrict__ ir,
                                                      const float* __restrict__ l8,
                                                      const float* __restrict__ l00,
                                                      const float* __restrict__ l01,
                                                      const float* __restrict__ l02,
                                                      const float* __restrict__ l03,
                                                      const float* __restrict__ lpgf,
                                                      float* __restrict__ out) {
#pragma clang fp contract(off)
    int p = blockIdx.x * 256 + threadIdx.x;
    if (p >= NPIX) return;
    int b  = p >> 18;
    int hw = p & (HW - 1);
    int vbase = (b * 3) << 18;

    const float* ptrs[6] = { l8, l00, l01, l02, l03, lpgf };

    float x0 = vi[vbase + hw];
    float x1 = vi[vbase + HW + hw];
    float x2 = vi[vbase + 2 * HW + hw];
    float x3 = ir[p];

    for (int s = 0; s < 6; ++s) {
        const float* __restrict__ L = ptrs[s];
        int n_ch = (s == 5) ? 3 : 4;
        x0 = fminf(fmaxf(x0, 0.f), 1.f);
        x1 = fminf(fmaxf(x1, 0.f), 1.f);
        x2 = fminf(fmaxf(x2, 0.f), 1.f);
        x3 = fminf(fmaxf(x3, 0.f), 1.f);
        float xs0 = x0 * 16.f;
        float xs1 = x1 * 16.f;
        float xs2 = x2 * 16.f;
        float xs3 = x3 * 16.f;
        int i0 = (int)xs0; i0 = i0 > 15 ? 15 : i0;
        int i1 = (int)xs1; i1 = i1 > 15 ? 15 : i1;
        int i2 = (int)xs2; i2 = i2 > 15 ? 15 : i2;
        int i3 = (int)xs3; i3 = i3 > 15 ? 15 : i3;
        float f0 = xs0 - (float)i0;
        float f1 = xs1 - (float)i1;
        float f2 = xs2 - (float)i2;
        float f3 = xs3 - (float)i3;
        float g0 = 1.f - f0;
        float g1 = 1.f - f1;
        float g2 = 1.f - f2;
        float g3 = 1.f - f3;
        float w01[4] = { g0 * g1, f0 * g1, g0 * f1, f0 * f1 };
        int off = i0 * 4913 + i1 * 289 + i2 * 17 + i3;
        float a0 = 0.f, a1 = 0.f, a2 = 0.f, a3 = 0.f;
        for (int cr = 0; cr < 16; ++cr) {
            int hi = cr >> 3, c = cr & 7;
            int idx = off + (c & 1) * 4913 + ((c >> 1) & 1) * 289 + (c >> 2) * 17 + hi;
            float w012 = w01[c & 3] * ((c >> 2) ? f2 : g2);
            float w    = w012 * (hi ? f3 : g3);
            float v0 = L[idx];
            float v1 = L[D4 + idx];
            float v2 = L[2 * D4 + idx];
            float v3 = (n_ch == 4) ? L[3 * D4 + idx] : 0.f;
            if (cr == 0) {
                a0 = v0 * w; a1 = v1 * w; a2 = v2 * w; a3 = v3 * w;
            } else {
                a0 = a0 + v0 * w; a1 = a1 + v1 * w;
                a2 = a2 + v2 * w; a3 = a3 + v3 * w;
            }
        }
        x0 = a0; x1 = a1; x2 = a2; x3 = a3;
    }

    out[vbase + hw]          = x0;
    out[vbase + HW + hw]     = x1;
    out[vbase + 2 * HW + hw] = x2;
}

extern "C" void kernel_launch(void* const* d_in, const int* in_sizes, int n_in,
                              void* d_out, int out_size, void* d_ws, size_t ws_size,
                              hipStream_t stream) {
    const float* vi = (const float*)d_in[0];
    const float* ir = (const float*)d_in[1];
    const float* raw[6] = {
        (const float*)d_in[2], (const float*)d_in[3],
        (const float*)d_in[4], (const float*)d_in[5],
        (const float*)d_in[6], (const float*)d_in[7]
    };
    float* out = (float*)d_out;

    const size_t OSZ      = (size_t)RECN * 128;              // 8,912,896 B/LUT
    const size_t NEED_OCT = 6 * OSZ;                         // ~53.5 MB
    const size_t QSZ      = (size_t)QREC * 64;               // 4,734,976 B/LUT
    const size_t NEED_Q   = 6 * QSZ;                         // ~28.4 MB

    if (ws_size >= NEED_OCT) {
        SrcPtrs sp;
        for (int s = 0; s < 6; ++s) sp.p[s] = raw[s];
        int pack_blocks = 6 * RECN * 8 / 256;                // 13056, exact
        pack_oct_all<<<pack_blocks, 256, 0, stream>>>(sp, (float4*)d_ws);
        fused_coop<<<NPIX / CBLK, CBLK, 0, stream>>>(vi, ir, (const float4*)d_ws, out);
    } else if (ws_size >= NEED_Q) {
        char* ws = (char*)d_ws;
        int pack_blocks = (QREC + 255) / 256;
        for (int s = 0; s < 6; ++s) {
            pack_quad<<<pack_blocks, 256, 0, stream>>>(raw[s], (s == 5) ? 3 : 4,
                                                       (float4*)(ws + s * QSZ));
        }
        fused_coop_q<<<NPIX / CBLK, CBLK, 0, stream>>>(vi, ir, (const float4*)ws, out);
    } else {
        fused_fallback<<<NPIX / 256, 256, 0, stream>>>(vi, ir, raw[0], raw[1], raw[2],
                                                       raw[3], raw[4], raw[5], out);
    }
}

// Round 7
// 276.265 us; speedup vs baseline: 1.1696x; 1.1696x over previous
//
#include <hip/hip_runtime.h>

// CRITICAL: bit-exact replication of the numpy fp32 oracle requires NO FMA
// contraction (hipcc default -ffp-contract=fast-honor-pragmas would fuse).
#pragma clang fp contract(off)

#define D4    83521      // 17^4 entries per LUT (per channel)
#define HW    262144     // 512*512
#define NPIX  2097152    // 8*512*512
#define QREC  73984      // 17*17*16*16 quad records per LUT (64 B each)
#define RECN  69632      // 17*16*16*16 oct records per LUT (128 B each)
#define CBLK  64         // cooperative kernel: single-wave blocks

struct SrcPtrs { const float* p[6]; };

typedef const __attribute__((address_space(1))) void* gptr_t;
typedef __attribute__((address_space(3))) void* lptr_t;

// ---------- oct packing, ALL 6 LUTS IN ONE LAUNCH ---------------------------
// Record e = ((i0*16 + i1)*16 + i2)*16 + i3 (i1,i2,i3 in [0,16), i0 in [0,17));
// slot g (float4) holds channels of corner (i1+((g>>2)&1), i2+((g>>1)&1),
// i3+(g&1)). A pixel's 16 corners = records R(i0) and R(i0)+4096 (i0+1),
// each ONE aligned 128 B line. One float4 slot per thread -> coalesced writes.
__global__ __launch_bounds__(256) void pack_oct_all(SrcPtrs sp,
                                                    float4* __restrict__ dst) {
    const int PER = RECN * 8;                 // 557056 slots per LUT
    int blk = blockIdx.x;
    int s = blk / 2176;                       // LUT index 0..5 (uniform/scalar)
    int j = blk * 256 + threadIdx.x;          // [0, 6*PER), grid exact
    int r = j - s * PER;
    int g = r & 7;                            // slot = b1*4 + b2*2 + b3
    int e = r >> 3;                           // record index
    int i3 = e & 15;
    int i2 = (e >> 4) & 15;
    int i1 = (e >> 8) & 15;
    int i0 = e >> 12;                         // [0,17)
    int o = i0 * 4913 + i1 * 289 + i2 * 17 + i3
          + ((g >> 2) & 1) * 289 + ((g >> 1) & 1) * 17 + (g & 1);
    const float* __restrict__ src = sp.p[s];
    float4 v;
    v.x = src[o];
    v.y = src[D4 + o];
    v.z = src[2 * D4 + o];
    v.w = (s != 5) ? src[3 * D4 + o] : 0.f;
    dst[j] = v;                               // fully coalesced 16 B/lane
}

// Cooperative fused 6-stage chain — DMA-GATHER (r20).
// r16/r19 proved the compiler will NEVER hold a 16-float4 load batch in
// VGPRs (stays at 64-68 regs, splits the batch -> ~2-deep pipelining,
// latency-bound at ~5.3K cy/stage). r20 removes the register payload
// entirely: __builtin_amdgcn_global_load_lds (16 B/lane, no dest VGPRs)
// issues all 16 gathers per stage truly back-to-back. The DMA writes lane
// l's 16 B to ldsbase + l*16, so with UNPADDED 16-float4 rows the linear
// slot 64t+l IS (row 4t+(l>>4), col l&15): the exchange happens inside the
// DMA. 256 B row stride would make fixed-col ds_reads a 16-way quarter-wave
// conflict, so the corner<->column mapping is XOR-swizzled (guide G4/#21):
// col m of row r holds corner m ^ (r&15); the reader uses myb[k ^ (tid&15)]
// (quarter-wave spans all 16 cols -> 2-way, free); the loader pre-swizzles
// the per-lane GLOBAL address (aoff[t], s-independent). Values and the
// sequential accumulation are bit-identical to r17 (absmax 0.0); only LDS
// placement changes. vmcnt(0) + sched_barrier before reads; next stage's
// DMA issue is data-dependent on this stage's accumulate (no WAR race).
__global__ __launch_bounds__(CBLK) void fused_coop(const float* __restrict__ vi,
                                                   const float* __restrict__ ir,
                                                   const float4* __restrict__ luts,
                                                   float* __restrict__ out) {
#pragma clang fp contract(off)
    __shared__ float4 exch[CBLK * 16];  // 16384 B: 64 rows x 16 float4, UNPADDED

    int tid = threadIdx.x;              // == lane (single-wave block)
    int p = blockIdx.x * CBLK + tid;
    int b  = p >> 18;                   // HW = 2^18
    int hw = p & (HW - 1);
    int vbase = (b * 3) << 18;

    float x0 = vi[vbase + hw];
    float x1 = vi[vbase + HW + hw];
    float x2 = vi[vbase + 2 * HW + hw];
    float x3 = ir[p];

    int sub = tid >> 4;                 // which pixel of each 4-px group
    int lo  = tid & 15;                 // column this lane's DMA lands in

    // per-(lane,t) corner pre-swizzle: col lo of row 4t+sub must hold corner
    // lo ^ ((4t+sub)&15).  aoff = b0*(4096 records)*8 + slot, in float4 units.
    // corner bits: b0=(c>>2)&1, b1=(c>>3)&1, b2=c&1, b3=(c>>1)&1 (r17 conv.)
    int aoff[16];
#pragma unroll
    for (int t = 0; t < 16; ++t) {
        int c = lo ^ ((4 * t + sub) & 15);
        aoff[t] = ((c >> 2) & 1) * (4096 * 8)
                + ((c >> 3) & 1) * 4 + (c & 1) * 2 + ((c >> 1) & 1);
    }

    for (int s = 0; s < 6; ++s) {
        const float4* __restrict__ lutS4 = luts + (size_t)s * (RECN * 8);

        // ---- owner: indices + weights (exact round-6 arithmetic) ----
        x0 = fminf(fmaxf(x0, 0.f), 1.f);
        x1 = fminf(fmaxf(x1, 0.f), 1.f);
        x2 = fminf(fmaxf(x2, 0.f), 1.f);
        x3 = fminf(fmaxf(x3, 0.f), 1.f);
        float xs0 = x0 * 16.f;
        float xs1 = x1 * 16.f;
        float xs2 = x2 * 16.f;
        float xs3 = x3 * 16.f;
        int i0 = (int)xs0; i0 = i0 > 15 ? 15 : i0;
        int i1 = (int)xs1; i1 = i1 > 15 ? 15 : i1;
        int i2 = (int)xs2; i2 = i2 > 15 ? 15 : i2;
        int i3 = (int)xs3; i3 = i3 > 15 ? 15 : i3;
        float f0 = xs0 - (float)i0;     // mul-then-sub, contraction OFF
        float f1 = xs1 - (float)i1;
        float f2 = xs2 - (float)i2;
        float f3 = xs3 - (float)i3;
        float g0 = 1.f - f0;
        float g1 = 1.f - f1;
        float g2 = 1.f - f2;
        float g3 = 1.f - f3;
        float w01[4] = { g0 * g1, f0 * g1, g0 * f1, f0 * f1 };

        int r00 = ((i0 * 16 + i1) * 16 + i2) * 16 + i3;   // oct record index

        // ---- r00 exchange: pure in-wave shuffle, no LDS / no barrier ----
        int r0s[16];
#pragma unroll
        for (int t = 0; t < 16; ++t)
            r0s[t] = __shfl(r00, 4 * t + sub, 64);

        // ---- DMA gather: 16 x global_load_lds, no dest VGPRs, all in
        //      flight; lane l's 16 B lands at exch[t*64 + l] ----
#pragma unroll
        for (int t = 0; t < 16; ++t) {
            const float4* gp = lutS4 + ((size_t)r0s[t] * 8 + aoff[t]);
            __builtin_amdgcn_global_load_lds((gptr_t)gp,
                                             (lptr_t)&exch[t * 64],
                                             16, 0, 0);
        }
        __builtin_amdgcn_sched_barrier(0);
        asm volatile("s_waitcnt vmcnt(0)" ::: "memory");  // all 16 DMAs landed
        __builtin_amdgcn_sched_barrier(0);

        // ---- owner: exact round-6 sequential accumulation ----
        // corner k sits at col k ^ lo of row tid (XOR-swizzled placement)
        const float4* myb = &exch[tid * 16];
        float a0 = 0.f, a1 = 0.f, a2 = 0.f, a3 = 0.f;
#pragma unroll
        for (int hi = 0; hi < 2; ++hi) {     // b3
            float w3 = hi ? f3 : g3;
#pragma unroll
            for (int c = 0; c < 8; ++c) {    // b0=c&1, b1=(c>>1)&1, b2=c>>2
                int k = ((c & 3) << 2) + ((c >> 2) + 2 * hi);  // 4b0+8b1+b2+2b3
                float4 vv = myb[k ^ lo];
                float w012 = w01[c & 3] * ((c >> 2) ? f2 : g2);
                float w    = w012 * w3;
                if (hi == 0 && c == 0) {
                    a0 = vv.x * w; a1 = vv.y * w; a2 = vv.z * w; a3 = vv.w * w;
                } else {
                    a0 = a0 + vv.x * w; a1 = a1 + vv.y * w;
                    a2 = a2 + vv.z * w; a3 = a3 + vv.w * w;
                }
            }
        }
        __builtin_amdgcn_sched_barrier(0);   // reads done before next stage's DMA
        x0 = a0; x1 = a1; x2 = a2; x3 = a3;
    }

    out[vbase + hw]          = x0;
    out[vbase + HW + hw]     = x1;
    out[vbase + 2 * HW + hw] = x2;
}

// ---------- quad tier (proven r13, 285 us coop): fallback if ws < 53.5 MB ---
__global__ __launch_bounds__(256) void pack_quad(const float* __restrict__ src,
                                                 int n_ch,
                                                 float4* __restrict__ dst) {
    int e = blockIdx.x * 256 + threadIdx.x;
    if (e >= QREC) return;
    int i3 = e & 15;
    int i2 = (e >> 4) & 15;
    int t  = e >> 8;              // i0*17 + i1
    int i0 = t / 17;
    int i1 = t - i0 * 17;
    int base = i0 * 4913 + i1 * 289 + i2 * 17 + i3;
    float4* rec = dst + (size_t)e * 4;
#pragma unroll
    for (int g = 0; g < 4; ++g) {
        int o = base + (g & 1) * 17 + (g >> 1);
        float4 v;
        v.x = src[o];
        v.y = src[D4 + o];
        v.z = src[2 * D4 + o];
        v.w = (n_ch == 4) ? src[3 * D4 + o] : 0.f;
        rec[g] = v;
    }
}

__global__ __launch_bounds__(CBLK) void fused_coop_q(const float* __restrict__ vi,
                                                     const float* __restrict__ ir,
                                                     const float4* __restrict__ luts,
                                                     float* __restrict__ out) {
#pragma clang fp contract(off)
    __shared__ float4 exch[CBLK * 17];

    int tid = threadIdx.x;
    int p = blockIdx.x * CBLK + tid;
    int b  = p >> 18;
    int hw = p & (HW - 1);
    int vbase = (b * 3) << 18;

    float x0 = vi[vbase + hw];
    float x1 = vi[vbase + HW + hw];
    float x2 = vi[vbase + 2 * HW + hw];
    float x3 = ir[p];

    int rec     = (tid >> 2) & 3;
    int slot    = tid & 3;
    int rec_off = ((rec & 1) ? 4352 : 0) + ((rec & 2) ? 256 : 0);
    int sub     = tid >> 4;
    int kidx    = tid & 15;

    for (int s = 0; s < 6; ++s) {
        const float4* __restrict__ lutS =
            luts + (size_t)s * QREC * 4 + (size_t)rec_off * 4 + slot;

        x0 = fminf(fmaxf(x0, 0.f), 1.f);
        x1 = fminf(fmaxf(x1, 0.f), 1.f);
        x2 = fminf(fmaxf(x2, 0.f), 1.f);
        x3 = fminf(fmaxf(x3, 0.f), 1.f);
        float xs0 = x0 * 16.f;
        float xs1 = x1 * 16.f;
        float xs2 = x2 * 16.f;
        float xs3 = x3 * 16.f;
        int i0 = (int)xs0; i0 = i0 > 15 ? 15 : i0;
        int i1 = (int)xs1; i1 = i1 > 15 ? 15 : i1;
        int i2 = (int)xs2; i2 = i2 > 15 ? 15 : i2;
        int i3 = (int)xs3; i3 = i3 > 15 ? 15 : i3;
        float f0 = xs0 - (float)i0;
        float f1 = xs1 - (float)i1;
        float f2 = xs2 - (float)i2;
        float f3 = xs3 - (float)i3;
        float g0 = 1.f - f0;
        float g1 = 1.f - f1;
        float g2 = 1.f - f2;
        float g3 = 1.f - f3;
        float w01[4] = { g0 * g1, f0 * g1, g0 * f1, f0 * f1 };

        int r00 = ((i0 * 17 + i1) * 16 + i2) * 16 + i3;

        int r0s[16];
#pragma unroll
        for (int t = 0; t < 16; ++t)
            r0s[t] = __shfl(r00, 4 * t + sub, 64);

        float4 v[16];
#pragma unroll
        for (int t = 0; t < 16; ++t)
            v[t] = lutS[(size_t)r0s[t] * 4];
        __builtin_amdgcn_sched_barrier(0);

#pragma unroll
        for (int t = 0; t < 16; ++t)
            exch[(4 * t + sub) * 17 + kidx] = v[t];
        __builtin_amdgcn_sched_barrier(0);

        const float4* myb = &exch[tid * 17];
        float a0 = 0.f, a1 = 0.f, a2 = 0.f, a3 = 0.f;
#pragma unroll
        for (int hi = 0; hi < 2; ++hi) {
            float w3 = hi ? f3 : g3;
#pragma unroll
            for (int c = 0; c < 8; ++c) {
                int k = ((c & 3) << 2) + ((c >> 2) + 2 * hi);
                float4 vv = myb[k];
                float w012 = w01[c & 3] * ((c >> 2) ? f2 : g2);
                float w    = w012 * w3;
                if (hi == 0 && c == 0) {
                    a0 = vv.x * w; a1 = vv.y * w; a2 = vv.z * w; a3 = vv.w * w;
                } else {
                    a0 = a0 + vv.x * w; a1 = a1 + vv.y * w;
                    a2 = a2 + vv.z * w; a3 = a3 + vv.w * w;
                }
            }
        }
        __builtin_amdgcn_sched_barrier(0);
        x0 = a0; x1 = a1; x2 = a2; x3 = a3;
    }

    out[vbase + hw]          = x0;
    out[vbase + HW + hw]     = x1;
    out[vbase + 2 * HW + hw] = x2;
}

// ---------- raw fallback (no workspace) -------------------------------------
__global__ __launch_bounds__(256) void fused_fallback(const float* __restrict__ vi,
                                                      const float* __restrict__ ir,
                                                      const float* __restrict__ l8,
                                                      const float* __restrict__ l00,
                                                      const float* __restrict__ l01,
                                                      const float* __restrict__ l02,
                                                      const float* __restrict__ l03,
                                                      const float* __restrict__ lpgf,
                                                      float* __restrict__ out) {
#pragma clang fp contract(off)
    int p = blockIdx.x * 256 + threadIdx.x;
    if (p >= NPIX) return;
    int b  = p >> 18;
    int hw = p & (HW - 1);
    int vbase = (b * 3) << 18;

    const float* ptrs[6] = { l8, l00, l01, l02, l03, lpgf };

    float x0 = vi[vbase + hw];
    float x1 = vi[vbase + HW + hw];
    float x2 = vi[vbase + 2 * HW + hw];
    float x3 = ir[p];

    for (int s = 0; s < 6; ++s) {
        const float* __restrict__ L = ptrs[s];
        int n_ch = (s == 5) ? 3 : 4;
        x0 = fminf(fmaxf(x0, 0.f), 1.f);
        x1 = fminf(fmaxf(x1, 0.f), 1.f);
        x2 = fminf(fmaxf(x2, 0.f), 1.f);
        x3 = fminf(fmaxf(x3, 0.f), 1.f);
        float xs0 = x0 * 16.f;
        float xs1 = x1 * 16.f;
        float xs2 = x2 * 16.f;
        float xs3 = x3 * 16.f;
        int i0 = (int)xs0; i0 = i0 > 15 ? 15 : i0;
        int i1 = (int)xs1; i1 = i1 > 15 ? 15 : i1;
        int i2 = (int)xs2; i2 = i2 > 15 ? 15 : i2;
        int i3 = (int)xs3; i3 = i3 > 15 ? 15 : i3;
        float f0 = xs0 - (float)i0;
        float f1 = xs1 - (float)i1;
        float f2 = xs2 - (float)i2;
        float f3 = xs3 - (float)i3;
        float g0 = 1.f - f0;
        float g1 = 1.f - f1;
        float g2 = 1.f - f2;
        float g3 = 1.f - f3;
        float w01[4] = { g0 * g1, f0 * g1, g0 * f1, f0 * f1 };
        int off = i0 * 4913 + i1 * 289 + i2 * 17 + i3;
        float a0 = 0.f, a1 = 0.f, a2 = 0.f, a3 = 0.f;
        for (int cr = 0; cr < 16; ++cr) {
            int hi = cr >> 3, c = cr & 7;
            int idx = off + (c & 1) * 4913 + ((c >> 1) & 1) * 289 + (c >> 2) * 17 + hi;
            float w012 = w01[c & 3] * ((c >> 2) ? f2 : g2);
            float w    = w012 * (hi ? f3 : g3);
            float v0 = L[idx];
            float v1 = L[D4 + idx];
            float v2 = L[2 * D4 + idx];
            float v3 = (n_ch == 4) ? L[3 * D4 + idx] : 0.f;
            if (cr == 0) {
                a0 = v0 * w; a1 = v1 * w; a2 = v2 * w; a3 = v3 * w;
            } else {
                a0 = a0 + v0 * w; a1 = a1 + v1 * w;
                a2 = a2 + v2 * w; a3 = a3 + v3 * w;
            }
        }
        x0 = a0; x1 = a1; x2 = a2; x3 = a3;
    }

    out[vbase + hw]          = x0;
    out[vbase + HW + hw]     = x1;
    out[vbase + 2 * HW + hw] = x2;
}

extern "C" void kernel_launch(void* const* d_in, const int* in_sizes, int n_in,
                              void* d_out, int out_size, void* d_ws, size_t ws_size,
                              hipStream_t stream) {
    const float* vi = (const float*)d_in[0];
    const float* ir = (const float*)d_in[1];
    const float* raw[6] = {
        (const float*)d_in[2], (const float*)d_in[3],
        (const float*)d_in[4], (const float*)d_in[5],
        (const float*)d_in[6], (const float*)d_in[7]
    };
    float* out = (float*)d_out;

    const size_t OSZ      = (size_t)RECN * 128;              // 8,912,896 B/LUT
    const size_t NEED_OCT = 6 * OSZ;                         // ~53.5 MB
    const size_t QSZ      = (size_t)QREC * 64;               // 4,734,976 B/LUT
    const size_t NEED_Q   = 6 * QSZ;                         // ~28.4 MB

    if (ws_size >= NEED_OCT) {
        SrcPtrs sp;
        for (int s = 0; s < 6; ++s) sp.p[s] = raw[s];
        int pack_blocks = 6 * RECN * 8 / 256;                // 13056, exact
        pack_oct_all<<<pack_blocks, 256, 0, stream>>>(sp, (float4*)d_ws);
        fused_coop<<<NPIX / CBLK, CBLK, 0, stream>>>(vi, ir, (const float4*)d_ws, out);
    } else if (ws_size >= NEED_Q) {
        char* ws = (char*)d_ws;
        int pack_blocks = (QREC + 255) / 256;
        for (int s = 0; s < 6; ++s) {
            pack_quad<<<pack_blocks, 256, 0, stream>>>(raw[s], (s == 5) ? 3 : 4,
                                                       (float4*)(ws + s * QSZ));
        }
        fused_coop_q<<<NPIX / CBLK, CBLK, 0, stream>>>(vi, ir, (const float4*)ws, out);
    } else {
        fused_fallback<<<NPIX / 256, 256, 0, stream>>>(vi, ir, raw[0], raw[1], raw[2],
                                                       raw[3], raw[4], raw[5], out);
    }
}

// Round 8
// 273.532 us; speedup vs baseline: 1.1813x; 1.0100x over previous
//
#include <hip/hip_runtime.h>

// CRITICAL: bit-exact replication of the numpy fp32 oracle requires NO FMA
// contraction (hipcc default -ffp-contract=fast-honor-pragmas would fuse).
#pragma clang fp contract(off)

#define D4    83521      // 17^4 entries per LUT (per channel)
#define HW    262144     // 512*512
#define NPIX  2097152    // 8*512*512
#define QREC  73984      // 17*17*16*16 quad records per LUT (64 B each)
#define RECN  69632      // 17*16*16*16 oct records per LUT (128 B each)
#define CBLK  64         // cooperative kernel: single-wave blocks

struct SrcPtrs { const float* p[6]; };

typedef const __attribute__((address_space(1))) void* gptr_t;
typedef __attribute__((address_space(3))) void* lptr_t;

// ---------- oct packing via LDS slab staging (r21) --------------------------
// r20's pack_oct_all read each source float with scattered 4 B scalar loads,
// amplified up to 8x (each float feeds 8 record slots). r21: one block per
// (lut s, i0, i1): stage the 2x289-float x 4-channel slab (9.2 KB) into LDS
// with COALESCED reads (each float read exactly once), barrier, then write
// the 2048 record-float4s (32 KB) fully coalesced. Output bytes/addresses
// are IDENTICAL to pack_oct_all (o-formula verbatim; s==5 -> w=0), so
// fused_coop's input is bit-identical.
// Record e = ((i0*16 + i1)*16 + i2)*16 + i3; slot g holds channels of corner
// (i1+(g>>2), i2+((g>>1)&1), i3+(g&1)).
__global__ __launch_bounds__(256) void pack_oct_lds(SrcPtrs sp,
                                                    float4* __restrict__ dst) {
    __shared__ float lds[2312];               // 4 ch x 2 di1 x 289
    int blk = blockIdx.x;                     // [0, 6*272)
    int s   = blk / 272;
    int rr  = blk - s * 272;
    int i0  = rr >> 4;                        // [0,17)
    int i1  = rr & 15;                        // [0,16)
    int tid = threadIdx.x;

    const float* __restrict__ src = sp.p[s];
    int base0 = i0 * 4913 + i1 * 289;

    // ---- stage: 2312 floats, coalesced (runs of 289), each read once ----
    for (int q = tid; q < 2312; q += 256) {
        int ch  = q / 578;                    // 0..3
        int rem = q - ch * 578;
        int di1 = rem / 289;                  // 0..1
        int r   = rem - di1 * 289;            // 0..288
        float v = 0.f;
        if (!(ch == 3 && s == 5))
            v = src[ch * D4 + base0 + di1 * 289 + r];
        lds[q] = v;
    }
    __syncthreads();

    // ---- emit: 2048 float4 (32 KB), fully coalesced ----
    const int PER = RECN * 8;                 // 557056 float4 per LUT
    float4* __restrict__ dblk =
        dst + (size_t)s * PER + (size_t)(i0 * 16 + i1) * 2048;
#pragma unroll
    for (int it = 0; it < 8; ++it) {
        int j2 = it * 256 + tid;              // [0,2048)
        int i2 = j2 >> 7;                     // [0,16)
        int i3 = (j2 >> 3) & 15;              // [0,16)
        int g  = j2 & 7;                      // slot
        int di1 = g >> 2;
        int pos = (i2 + ((g >> 1) & 1)) * 17 + i3 + (g & 1);
        int l   = di1 * 289 + pos;
        float4 v;
        v.x = lds[l];
        v.y = lds[578 + l];
        v.z = lds[1156 + l];
        v.w = lds[1734 + l];
        dblk[j2] = v;
    }
}

// Cooperative fused 6-stage chain — DMA-GATHER (r20, FROZEN at 185 us).
// Diagnosis r13/r17/r20: demand is at the structural floor (2 x 128 B lines
// per pixel per stage) and the time is invariant across 2-deep (r17) and
// 16-deep (r20) pipelines -> the L2/TD random-gather service rate
// (~4.5 cy/line/CU, 17.4 TB/s aggregate, ~half streaming L2) is the wall.
// __builtin_amdgcn_global_load_lds (16 B/lane, no dest VGPRs) issues all 16
// gathers back-to-back; lane l's 16 B lands at ldsbase + l*16, so with
// unpadded 16-float4 rows the linear slot 64t+l IS (row 4t+(l>>4), col l&15):
// the exchange happens inside the DMA. The corner<->column mapping is
// XOR-swizzled (col m of row r holds corner m ^ (r&15)); the reader uses
// myb[k ^ lo]; the loader pre-swizzles the per-lane GLOBAL address (aoff[t]).
// Values and accumulation order bit-identical to r17 (absmax 0.0).
__global__ __launch_bounds__(CBLK) void fused_coop(const float* __restrict__ vi,
                                                   const float* __restrict__ ir,
                                                   const float4* __restrict__ luts,
                                                   float* __restrict__ out) {
#pragma clang fp contract(off)
    __shared__ float4 exch[CBLK * 16];  // 16384 B: 64 rows x 16 float4, UNPADDED

    int tid = threadIdx.x;              // == lane (single-wave block)
    int p = blockIdx.x * CBLK + tid;
    int b  = p >> 18;                   // HW = 2^18
    int hw = p & (HW - 1);
    int vbase = (b * 3) << 18;

    float x0 = vi[vbase + hw];
    float x1 = vi[vbase + HW + hw];
    float x2 = vi[vbase + 2 * HW + hw];
    float x3 = ir[p];

    int sub = tid >> 4;                 // which pixel of each 4-px group
    int lo  = tid & 15;                 // column this lane's DMA lands in

    // per-(lane,t) corner pre-swizzle: col lo of row 4t+sub must hold corner
    // lo ^ ((4t+sub)&15).  aoff = b0*(4096 records)*8 + slot, in float4 units.
    // corner bits: b0=(c>>2)&1, b1=(c>>3)&1, b2=c&1, b3=(c>>1)&1 (r17 conv.)
    int aoff[16];
#pragma unroll
    for (int t = 0; t < 16; ++t) {
        int c = lo ^ ((4 * t + sub) & 15);
        aoff[t] = ((c >> 2) & 1) * (4096 * 8)
                + ((c >> 3) & 1) * 4 + (c & 1) * 2 + ((c >> 1) & 1);
    }

    for (int s = 0; s < 6; ++s) {
        const float4* __restrict__ lutS4 = luts + (size_t)s * (RECN * 8);

        // ---- owner: indices + weights (exact round-6 arithmetic) ----
        x0 = fminf(fmaxf(x0, 0.f), 1.f);
        x1 = fminf(fmaxf(x1, 0.f), 1.f);
        x2 = fminf(fmaxf(x2, 0.f), 1.f);
        x3 = fminf(fmaxf(x3, 0.f), 1.f);
        float xs0 = x0 * 16.f;
        float xs1 = x1 * 16.f;
        float xs2 = x2 * 16.f;
        float xs3 = x3 * 16.f;
        int i0 = (int)xs0; i0 = i0 > 15 ? 15 : i0;
        int i1 = (int)xs1; i1 = i1 > 15 ? 15 : i1;
        int i2 = (int)xs2; i2 = i2 > 15 ? 15 : i2;
        int i3 = (int)xs3; i3 = i3 > 15 ? 15 : i3;
        float f0 = xs0 - (float)i0;     // mul-then-sub, contraction OFF
        float f1 = xs1 - (float)i1;
        float f2 = xs2 - (float)i2;
        float f3 = xs3 - (float)i3;
        float g0 = 1.f - f0;
        float g1 = 1.f - f1;
        float g2 = 1.f - f2;
        float g3 = 1.f - f3;
        float w01[4] = { g0 * g1, f0 * g1, g0 * f1, f0 * f1 };

        int r00 = ((i0 * 16 + i1) * 16 + i2) * 16 + i3;   // oct record index

        // ---- r00 exchange: pure in-wave shuffle, no LDS / no barrier ----
        int r0s[16];
#pragma unroll
        for (int t = 0; t < 16; ++t)
            r0s[t] = __shfl(r00, 4 * t + sub, 64);

        // ---- DMA gather: 16 x global_load_lds, no dest VGPRs, all in
        //      flight; lane l's 16 B lands at exch[t*64 + l] ----
#pragma unroll
        for (int t = 0; t < 16; ++t) {
            const float4* gp = lutS4 + ((size_t)r0s[t] * 8 + aoff[t]);
            __builtin_amdgcn_global_load_lds((gptr_t)gp,
                                             (lptr_t)&exch[t * 64],
                                             16, 0, 0);
        }
        __builtin_amdgcn_sched_barrier(0);
        asm volatile("s_waitcnt vmcnt(0)" ::: "memory");  // all 16 DMAs landed
        __builtin_amdgcn_sched_barrier(0);

        // ---- owner: exact round-6 sequential accumulation ----
        // corner k sits at col k ^ lo of row tid (XOR-swizzled placement)
        const float4* myb = &exch[tid * 16];
        float a0 = 0.f, a1 = 0.f, a2 = 0.f, a3 = 0.f;
#pragma unroll
        for (int hi = 0; hi < 2; ++hi) {     // b3
            float w3 = hi ? f3 : g3;
#pragma unroll
            for (int c = 0; c < 8; ++c) {    // b0=c&1, b1=(c>>1)&1, b2=c>>2
                int k = ((c & 3) << 2) + ((c >> 2) + 2 * hi);  // 4b0+8b1+b2+2b3
                float4 vv = myb[k ^ lo];
                float w012 = w01[c & 3] * ((c >> 2) ? f2 : g2);
                float w    = w012 * w3;
                if (hi == 0 && c == 0) {
                    a0 = vv.x * w; a1 = vv.y * w; a2 = vv.z * w; a3 = vv.w * w;
                } else {
                    a0 = a0 + vv.x * w; a1 = a1 + vv.y * w;
                    a2 = a2 + vv.z * w; a3 = a3 + vv.w * w;
                }
            }
        }
        __builtin_amdgcn_sched_barrier(0);   // reads done before next stage's DMA
        x0 = a0; x1 = a1; x2 = a2; x3 = a3;
    }

    out[vbase + hw]          = x0;
    out[vbase + HW + hw]     = x1;
    out[vbase + 2 * HW + hw] = x2;
}

// ---------- quad tier (proven r13, 285 us coop): fallback if ws < 53.5 MB ---
__global__ __launch_bounds__(256) void pack_quad(const float* __restrict__ src,
                                                 int n_ch,
                                                 float4* __restrict__ dst) {
    int e = blockIdx.x * 256 + threadIdx.x;
    if (e >= QREC) return;
    int i3 = e & 15;
    int i2 = (e >> 4) & 15;
    int t  = e >> 8;              // i0*17 + i1
    int i0 = t / 17;
    int i1 = t - i0 * 17;
    int base = i0 * 4913 + i1 * 289 + i2 * 17 + i3;
    float4* rec = dst + (size_t)e * 4;
#pragma unroll
    for (int g = 0; g < 4; ++g) {
        int o = base + (g & 1) * 17 + (g >> 1);
        float4 v;
        v.x = src[o];
        v.y = src[D4 + o];
        v.z = src[2 * D4 + o];
        v.w = (n_ch == 4) ? src[3 * D4 + o] : 0.f;
        rec[g] = v;
    }
}

__global__ __launch_bounds__(CBLK) void fused_coop_q(const float* __restrict__ vi,
                                                     const float* __restrict__ ir,
                                                     const float4* __restrict__ luts,
                                                     float* __restrict__ out) {
#pragma clang fp contract(off)
    __shared__ float4 exch[CBLK * 17];

    int tid = threadIdx.x;
    int p = blockIdx.x * CBLK + tid;
    int b  = p >> 18;
    int hw = p & (HW - 1);
    int vbase = (b * 3) << 18;

    float x0 = vi[vbase + hw];
    float x1 = vi[vbase + HW + hw];
    float x2 = vi[vbase + 2 * HW + hw];
    float x3 = ir[p];

    int rec     = (tid >> 2) & 3;
    int slot    = tid & 3;
    int rec_off = ((rec & 1) ? 4352 : 0) + ((rec & 2) ? 256 : 0);
    int sub     = tid >> 4;
    int kidx    = tid & 15;

    for (int s = 0; s < 6; ++s) {
        const float4* __restrict__ lutS =
            luts + (size_t)s * QREC * 4 + (size_t)rec_off * 4 + slot;

        x0 = fminf(fmaxf(x0, 0.f), 1.f);
        x1 = fminf(fmaxf(x1, 0.f), 1.f);
        x2 = fminf(fmaxf(x2, 0.f), 1.f);
        x3 = fminf(fmaxf(x3, 0.f), 1.f);
        float xs0 = x0 * 16.f;
        float xs1 = x1 * 16.f;
        float xs2 = x2 * 16.f;
        float xs3 = x3 * 16.f;
        int i0 = (int)xs0; i0 = i0 > 15 ? 15 : i0;
        int i1 = (int)xs1; i1 = i1 > 15 ? 15 : i1;
        int i2 = (int)xs2; i2 = i2 > 15 ? 15 : i2;
        int i3 = (int)xs3; i3 = i3 > 15 ? 15 : i3;
        float f0 = xs0 - (float)i0;
        float f1 = xs1 - (float)i1;
        float f2 = xs2 - (float)i2;
        float f3 = xs3 - (float)i3;
        float g0 = 1.f - f0;
        float g1 = 1.f - f1;
        float g2 = 1.f - f2;
        float g3 = 1.f - f3;
        float w01[4] = { g0 * g1, f0 * g1, g0 * f1, f0 * f1 };

        int r00 = ((i0 * 17 + i1) * 16 + i2) * 16 + i3;

        int r0s[16];
#pragma unroll
        for (int t = 0; t < 16; ++t)
            r0s[t] = __shfl(r00, 4 * t + sub, 64);

        float4 v[16];
#pragma unroll
        for (int t = 0; t < 16; ++t)
            v[t] = lutS[(size_t)r0s[t] * 4];
        __builtin_amdgcn_sched_barrier(0);

#pragma unroll
        for (int t = 0; t < 16; ++t)
            exch[(4 * t + sub) * 17 + kidx] = v[t];
        __builtin_amdgcn_sched_barrier(0);

        const float4* myb = &exch[tid * 17];
        float a0 = 0.f, a1 = 0.f, a2 = 0.f, a3 = 0.f;
#pragma unroll
        for (int hi = 0; hi < 2; ++hi) {
            float w3 = hi ? f3 : g3;
#pragma unroll
            for (int c = 0; c < 8; ++c) {
                int k = ((c & 3) << 2) + ((c >> 2) + 2 * hi);
                float4 vv = myb[k];
                float w012 = w01[c & 3] * ((c >> 2) ? f2 : g2);
                float w    = w012 * w3;
                if (hi == 0 && c == 0) {
                    a0 = vv.x * w; a1 = vv.y * w; a2 = vv.z * w; a3 = vv.w * w;
                } else {
                    a0 = a0 + vv.x * w; a1 = a1 + vv.y * w;
                    a2 = a2 + vv.z * w; a3 = a3 + vv.w * w;
                }
            }
        }
        __builtin_amdgcn_sched_barrier(0);
        x0 = a0; x1 = a1; x2 = a2; x3 = a3;
    }

    out[vbase + hw]          = x0;
    out[vbase + HW + hw]     = x1;
    out[vbase + 2 * HW + hw] = x2;
}

// ---------- raw fallback (no workspace) -------------------------------------
__global__ __launch_bounds__(256) void fused_fallback(const float* __restrict__ vi,
                                                      const float* __restrict__ ir,
                                                      const float* __restrict__ l8,
                                                      const float* __restrict__ l00,
                                                      const float* __restrict__ l01,
                                                      const float* __restrict__ l02,
                                                      const float* __restrict__ l03,
                                                      const float* __restrict__ lpgf,
                                                      float* __restrict__ out) {
#pragma clang fp contract(off)
    int p = blockIdx.x * 256 + threadIdx.x;
    if (p >= NPIX) return;
    int b  = p >> 18;
    int hw = p & (HW - 1);
    int vbase = (b * 3) << 18;

    const float* ptrs[6] = { l8, l00, l01, l02, l03, lpgf };

    float x0 = vi[vbase + hw];
    float x1 = vi[vbase + HW + hw];
    float x2 = vi[vbase + 2 * HW + hw];
    float x3 = ir[p];

    for (int s = 0; s < 6; ++s) {
        const float* __restrict__ L = ptrs[s];
        int n_ch = (s == 5) ? 3 : 4;
        x0 = fminf(fmaxf(x0, 0.f), 1.f);
        x1 = fminf(fmaxf(x1, 0.f), 1.f);
        x2 = fminf(fmaxf(x2, 0.f), 1.f);
        x3 = fminf(fmaxf(x3, 0.f), 1.f);
        float xs0 = x0 * 16.f;
        float xs1 = x1 * 16.f;
        float xs2 = x2 * 16.f;
        float xs3 = x3 * 16.f;
        int i0 = (int)xs0; i0 = i0 > 15 ? 15 : i0;
        int i1 = (int)xs1; i1 = i1 > 15 ? 15 : i1;
        int i2 = (int)xs2; i2 = i2 > 15 ? 15 : i2;
        int i3 = (int)xs3; i3 = i3 > 15 ? 15 : i3;
        float f0 = xs0 - (float)i0;
        float f1 = xs1 - (float)i1;
        float f2 = xs2 - (float)i2;
        float f3 = xs3 - (float)i3;
        float g0 = 1.f - f0;
        float g1 = 1.f - f1;
        float g2 = 1.f - f2;
        float g3 = 1.f - f3;
        float w01[4] = { g0 * g1, f0 * g1, g0 * f1, f0 * f1 };
        int off = i0 * 4913 + i1 * 289 + i2 * 17 + i3;
        float a0 = 0.f, a1 = 0.f, a2 = 0.f, a3 = 0.f;
        for (int cr = 0; cr < 16; ++cr) {
            int hi = cr >> 3, c = cr & 7;
            int idx = off + (c & 1) * 4913 + ((c >> 1) & 1) * 289 + (c >> 2) * 17 + hi;
            float w012 = w01[c & 3] * ((c >> 2) ? f2 : g2);
            float w    = w012 * (hi ? f3 : g3);
            float v0 = L[idx];
            float v1 = L[D4 + idx];
            float v2 = L[2 * D4 + idx];
            float v3 = (n_ch == 4) ? L[3 * D4 + idx] : 0.f;
            if (cr == 0) {
                a0 = v0 * w; a1 = v1 * w; a2 = v2 * w; a3 = v3 * w;
            } else {
                a0 = a0 + v0 * w; a1 = a1 + v1 * w;
                a2 = a2 + v2 * w; a3 = a3 + v3 * w;
            }
        }
        x0 = a0; x1 = a1; x2 = a2; x3 = a3;
    }

    out[vbase + hw]          = x0;
    out[vbase + HW + hw]     = x1;
    out[vbase + 2 * HW + hw] = x2;
}

extern "C" void kernel_launch(void* const* d_in, const int* in_sizes, int n_in,
                              void* d_out, int out_size, void* d_ws, size_t ws_size,
                              hipStream_t stream) {
    const float* vi = (const float*)d_in[0];
    const float* ir = (const float*)d_in[1];
    const float* raw[6] = {
        (const float*)d_in[2], (const float*)d_in[3],
        (const float*)d_in[4], (const float*)d_in[5],
        (const float*)d_in[6], (const float*)d_in[7]
    };
    float* out = (float*)d_out;

    const size_t OSZ      = (size_t)RECN * 128;              // 8,912,896 B/LUT
    const size_t NEED_OCT = 6 * OSZ;                         // ~53.5 MB
    const size_t QSZ      = (size_t)QREC * 64;               // 4,734,976 B/LUT
    const size_t NEED_Q   = 6 * QSZ;                         // ~28.4 MB

    if (ws_size >= NEED_OCT) {
        SrcPtrs sp;
        for (int s = 0; s < 6; ++s) sp.p[s] = raw[s];
        pack_oct_lds<<<6 * 272, 256, 0, stream>>>(sp, (float4*)d_ws);
        fused_coop<<<NPIX / CBLK, CBLK, 0, stream>>>(vi, ir, (const float4*)d_ws, out);
    } else if (ws_size >= NEED_Q) {
        char* ws = (char*)d_ws;
        int pack_blocks = (QREC + 255) / 256;
        for (int s = 0; s < 6; ++s) {
            pack_quad<<<pack_blocks, 256, 0, stream>>>(raw[s], (s == 5) ? 3 : 4,
                                                       (float4*)(ws + s * QSZ));
        }
        fused_coop_q<<<NPIX / CBLK, CBLK, 0, stream>>>(vi, ir, (const float4*)ws, out);
    } else {
        fused_fallback<<<NPIX / 256, 256, 0, stream>>>(vi, ir, raw[0], raw[1], raw[2],
                                                       raw[3], raw[4], raw[5], out);
    }
}